// Round 2
// baseline (210.696 us; speedup 1.0000x reference)
//
#include <hip/hip_runtime.h>
#include <stdint.h>

// Problem constants (match reference)
#define HH 1024
#define WW 2048
#define GG 256          // gt boxes per image
#define RRN 16384       // rois per image
#define NN 16640        // R + G, = 65*256 exactly
#define BB 8
#define NUM_POS_MAX 32
#define NUM_TOTAL 128
#define CAP 1024        // candidate capacity in select kernel

// ---------------------------------------------------------------------------
// Kernel 0: zero the workspace counters + sampled_ids (ws is poisoned 0xAA)
// ---------------------------------------------------------------------------
__global__ __launch_bounds__(1024) void init_kernel(int* __restrict__ pos_count,
                                                    int* __restrict__ sampled_ids) {
    int tid = threadIdx.x;
    if (tid < BB * NUM_TOTAL) sampled_ids[tid] = 0;
    if (tid < BB) pos_count[tid] = 0;
}

// ---------------------------------------------------------------------------
// Kernel 1: per-roi IoU max/argmax vs 256 gt boxes; pos mask; pos_count
// codes[b*N+i] = argmax | (pos ? 0x10000 : 0)
// ---------------------------------------------------------------------------
__global__ __launch_bounds__(256) void iou_kernel(const float* __restrict__ gt,
                                                  const float* __restrict__ rois,
                                                  uint32_t* __restrict__ codes,
                                                  int* __restrict__ pos_count) {
#pragma clang fp contract(off)
    __shared__ float4 sg[GG];
    __shared__ float sa2[GG];
    int b = blockIdx.x / 65;
    int chunk = blockIdx.x % 65;
    int tid = threadIdx.x;

    // stage gt boxes + their clipped areas
    float4 g = reinterpret_cast<const float4*>(gt)[b * GG + tid];
    sg[tid] = g;
    sa2[tid] = fmaxf((g.z - g.x) * (g.w - g.y), 0.0f);
    __syncthreads();

    int i = chunk * 256 + tid;  // 0..N-1, exact (N = 65*256)
    float4 rb;
    if (i < RRN) {
        rb = reinterpret_cast<const float4*>(rois)[b * RRN + i];
    } else {
        float4 gp = sg[i - RRN];
        rb = make_float4(gp.x / (float)WW, gp.y / (float)HH,
                         gp.z / (float)WW, gp.w / (float)HH);
    }
    float a1 = fmaxf((rb.z - rb.x) * (rb.w - rb.y), 0.0f);

    float best = -1.0f;
    int bestj = 0;
    for (int j = 0; j < GG; ++j) {
        float4 gj = sg[j];
        float lx = fmaxf(rb.x, gj.x);
        float ly = fmaxf(rb.y, gj.y);
        float ux = fminf(rb.z, gj.z);
        float uy = fminf(rb.w, gj.w);
        float iw = fmaxf(ux - lx, 0.0f);
        float ih = fmaxf(uy - ly, 0.0f);
        float inter = iw * ih;
        float denom = (a1 + sa2[j]) - inter;
        float iou = inter / denom;
        if (iou > best) { best = iou; bestj = j; }  // strict > keeps first max
    }

    bool pos = (best >= 0.5f);  // POS_THR; neg == !pos since iou_max >= 0
    codes[b * NN + i] = (uint32_t)bestj | (pos ? 0x10000u : 0u);

    unsigned long long m = __ballot(pos);
    if ((tid & 63) == 0) atomicAdd(&pos_count[b], __popcll(m));
}

// ---------------------------------------------------------------------------
// Kernel 2: exact stable top-k selection by random key. 16 blocks: (b, type)
// type 0 = positives (k = min(pos_count,32)), type 1 = negatives
// (k = min(N - pos_count, 128 - num_pos)). slot = rank (+num_pos for neg).
// ---------------------------------------------------------------------------
__global__ __launch_bounds__(256) void select_kernel(const uint32_t* __restrict__ codes,
                                                     const float* __restrict__ rp,
                                                     const float* __restrict__ rn,
                                                     const int* __restrict__ pos_count,
                                                     int* __restrict__ sampled_ids) {
    __shared__ uint32_t hist[1024];
    __shared__ uint32_t cbits[CAP];
    __shared__ int cidx[CAP];
    __shared__ int s_cnt, s_k, s_p, s_np;

    int b = blockIdx.x >> 1;
    int t = blockIdx.x & 1;
    int tid = threadIdx.x;
    const float* rnd = (t == 0) ? rp : rn;

    for (int j = tid; j < 1024; j += 256) hist[j] = 0u;
    if (tid == 0) s_cnt = 0;
    __syncthreads();

    // histogram of rand-key float bits (keys in [0,1) -> bits>>20 <= 1015)
    for (int i = tid; i < NN; i += 256) {
        uint32_t code = codes[b * NN + i];
        bool pos = (code & 0x10000u) != 0u;
        bool m = (t == 0) ? pos : !pos;
        if (m) {
            uint32_t bits = __float_as_uint(rnd[b * NN + i]);
            atomicAdd(&hist[bits >> 20], 1u);
        }
    }
    __syncthreads();

    if (tid == 0) {
        int pc = pos_count[b];
        int np_ = min(pc, NUM_POS_MAX);
        int k = (t == 0) ? np_ : min(NN - pc, NUM_TOTAL - np_);
        s_np = np_;
        s_k = k;
        int p = -1;
        if (k > 0) {
            int cum = 0;
            for (int j = 0; j < 1024; ++j) {
                cum += (int)hist[j];
                if (cum >= k) { p = j; break; }
            }
        }
        s_p = p;
    }
    __syncthreads();

    int p = s_p;
    int k = s_k;
    if (p >= 0) {
        for (int i = tid; i < NN; i += 256) {
            uint32_t code = codes[b * NN + i];
            bool pos = (code & 0x10000u) != 0u;
            bool m = (t == 0) ? pos : !pos;
            if (m) {
                uint32_t bits = __float_as_uint(rnd[b * NN + i]);
                if ((int)(bits >> 20) <= p) {
                    int idx = atomicAdd(&s_cnt, 1);
                    if (idx < CAP) { cbits[idx] = bits; cidx[idx] = i; }
                }
            }
        }
    }
    __syncthreads();

    int c = min(s_cnt, CAP);
    for (int ci = tid; ci < c; ci += 256) {
        uint32_t mb = cbits[ci];
        int mi = cidx[ci];
        int r = 0;
        for (int j = 0; j < c; ++j) {
            uint32_t ob = cbits[j];
            r += (ob < mb) || (ob == mb && cidx[j] < mi);  // stable rank
        }
        if (r < k) {
            int slot = (t == 0) ? r : (s_np + r);
            sampled_ids[b * NUM_TOTAL + slot] = mi;
        }
    }
}

// ---------------------------------------------------------------------------
// Kernel 3: gather + encode epilogue. Outputs (all as float32, concatenated):
//   [0,1024)            labels (cast int->float)
//   [1024,1024+4096)    encoded bboxes
//   [5120,5120+4096)    sampled rois
// ---------------------------------------------------------------------------
__global__ __launch_bounds__(256) void gather_kernel(const float* __restrict__ gt,
                                                     const int* __restrict__ gl,
                                                     const float* __restrict__ rois,
                                                     const uint32_t* __restrict__ codes,
                                                     const int* __restrict__ pos_count,
                                                     const int* __restrict__ sampled_ids,
                                                     float* __restrict__ out) {
#pragma clang fp contract(off)
    int gid = blockIdx.x * 256 + threadIdx.x;
    if (gid >= BB * NUM_TOTAL) return;
    int b = gid >> 7;
    int s = gid & 127;

    int id = sampled_ids[gid];
    uint32_t code = codes[b * NN + id];
    int amax = (int)(code & 0xFFFFu);
    int np_ = min(pos_count[b], NUM_POS_MAX);
    int label = (s < np_) ? (gl[b * GG + amax] + 1) : 0;

    float4 tb = reinterpret_cast<const float4*>(gt)[b * GG + amax];  // pixel gt
    float4 ar;
    if (id < RRN) {
        ar = reinterpret_cast<const float4*>(rois)[b * RRN + id];
    } else {
        float4 gp = reinterpret_cast<const float4*>(gt)[b * GG + (id - RRN)];
        ar = make_float4(gp.x / (float)WW, gp.y / (float)HH,
                         gp.z / (float)WW, gp.w / (float)HH);
    }

    // _xy2cxcy (NOTE reference halves wh too) then _encode then /std
    float acx = (ar.z + ar.x) / 2.0f, acy = (ar.w + ar.y) / 2.0f;
    float aw  = (ar.z - ar.x) / 2.0f, ah  = (ar.w - ar.y) / 2.0f;
    float gcx = (tb.z + tb.x) / 2.0f, gcy = (tb.w + tb.y) / 2.0f;
    float gw  = (tb.z - tb.x) / 2.0f, gh  = (tb.w - tb.y) / 2.0f;

    float e0 = ((gcx - acx) / aw) / 0.1f;
    float e1 = ((gcy - acy) / ah) / 0.1f;
    float e2 = logf(gw / aw) / 0.2f;
    float e3 = logf(gh / ah) / 0.2f;

    out[gid] = (float)label;
    float* eo = out + BB * NUM_TOTAL + gid * 4;
    eo[0] = e0; eo[1] = e1; eo[2] = e2; eo[3] = e3;
    float* ro = out + BB * NUM_TOTAL + BB * NUM_TOTAL * 4 + gid * 4;
    ro[0] = ar.x; ro[1] = ar.y; ro[2] = ar.z; ro[3] = ar.w;
}

// ---------------------------------------------------------------------------
extern "C" void kernel_launch(void* const* d_in, const int* in_sizes, int n_in,
                              void* d_out, int out_size, void* d_ws, size_t ws_size,
                              hipStream_t stream) {
    const float* gt   = (const float*)d_in[0];   // (B,G,4) f32
    const int*   gl   = (const int*)d_in[1];     // (B,G)   i32
    const float* rois = (const float*)d_in[2];   // (B,R,4) f32
    const float* rp   = (const float*)d_in[3];   // (B,N)   f32
    const float* rn   = (const float*)d_in[4];   // (B,N)   f32
    float* out = (float*)d_out;

    uint32_t* codes = (uint32_t*)d_ws;                         // B*N u32
    int* pos_count = (int*)((char*)d_ws + (size_t)BB * NN * 4);
    int* sampled_ids = pos_count + BB;                         // B*128 i32

    hipLaunchKernelGGL(init_kernel, dim3(1), dim3(1024), 0, stream,
                       pos_count, sampled_ids);
    hipLaunchKernelGGL(iou_kernel, dim3(BB * 65), dim3(256), 0, stream,
                       gt, rois, codes, pos_count);
    hipLaunchKernelGGL(select_kernel, dim3(BB * 2), dim3(256), 0, stream,
                       codes, rp, rn, pos_count, sampled_ids);
    hipLaunchKernelGGL(gather_kernel, dim3((BB * NUM_TOTAL + 255) / 256), dim3(256),
                       0, stream, gt, gl, rois, codes, pos_count, sampled_ids, out);
}

// Round 4
// 114.214 us; speedup vs baseline: 1.8447x; 1.8447x over previous
//
#include <hip/hip_runtime.h>
#include <stdint.h>

// Problem constants (match reference)
#define HH 1024
#define WW 2048
#define GG 256          // gt boxes per image
#define RRN 16384       // rois per image
#define NN 16640        // R + G, = 65*256 exactly
#define NV (NN / 4)     // 4160 uint4/float4 vectors per image
#define BB 8
#define NUM_POS_MAX 32
#define NUM_TOTAL 128
#define CAP 1024        // candidate capacity in select kernel
#define SEL_T 1024      // select block size

// ---------------------------------------------------------------------------
// Kernel 1: per-roi IoU max/argmax vs 256 gt boxes
// codes[b*N+i] = argmax | (pos ? 0x10000 : 0)
// ---------------------------------------------------------------------------
__global__ __launch_bounds__(256) void iou_kernel(const float* __restrict__ gt,
                                                  const float* __restrict__ rois,
                                                  uint32_t* __restrict__ codes) {
#pragma clang fp contract(off)
    __shared__ float4 sg[GG];
    __shared__ float sa2[GG];
    int b = blockIdx.x / 65;
    int chunk = blockIdx.x % 65;
    int tid = threadIdx.x;

    // stage gt boxes + their clipped areas
    float4 g = reinterpret_cast<const float4*>(gt)[b * GG + tid];
    sg[tid] = g;
    sa2[tid] = fmaxf((g.z - g.x) * (g.w - g.y), 0.0f);
    __syncthreads();

    int i = chunk * 256 + tid;  // 0..N-1, exact (N = 65*256)
    float4 rb;
    if (i < RRN) {
        rb = reinterpret_cast<const float4*>(rois)[b * RRN + i];
    } else {
        float4 gp = sg[i - RRN];
        rb = make_float4(gp.x / (float)WW, gp.y / (float)HH,
                         gp.z / (float)WW, gp.w / (float)HH);
    }
    float a1 = fmaxf((rb.z - rb.x) * (rb.w - rb.y), 0.0f);

    float best = -1.0f;
    int bestj = 0;
    for (int j = 0; j < GG; ++j) {
        float4 gj = sg[j];
        float lx = fmaxf(rb.x, gj.x);
        float ly = fmaxf(rb.y, gj.y);
        float ux = fminf(rb.z, gj.z);
        float uy = fminf(rb.w, gj.w);
        float iw = fmaxf(ux - lx, 0.0f);
        float ih = fmaxf(uy - ly, 0.0f);
        float inter = iw * ih;
        float denom = (a1 + sa2[j]) - inter;
        float iou = inter / denom;
        if (iou > best) { best = iou; bestj = j; }  // strict > keeps first max
    }

    bool pos = (best >= 0.5f);  // POS_THR; neg == !pos since iou_max >= 0
    codes[b * NN + i] = (uint32_t)bestj | (pos ? 0x10000u : 0u);
}

// ---------------------------------------------------------------------------
// Epilogue: write one sampled slot (label + encoded bbox + sampled roi)
// Output layout (all f32, concatenated): [0,1024) labels, [1024,5120) encoded,
// [5120,9216) sampled rois.
// ---------------------------------------------------------------------------
__device__ __forceinline__ void write_sample(int b, int s, int mi, int np,
                                             const float* __restrict__ gt,
                                             const int* __restrict__ gl,
                                             const float* __restrict__ rois,
                                             const uint32_t* __restrict__ codes,
                                             float* __restrict__ out) {
#pragma clang fp contract(off)
    uint32_t code = codes[b * NN + mi];
    int amax = (int)(code & 0xFFFFu);
    int label = (s < np) ? (gl[b * GG + amax] + 1) : 0;

    float4 tb = reinterpret_cast<const float4*>(gt)[b * GG + amax];  // pixel gt
    float4 ar;
    if (mi < RRN) {
        ar = reinterpret_cast<const float4*>(rois)[b * RRN + mi];
    } else {
        float4 gp = reinterpret_cast<const float4*>(gt)[b * GG + (mi - RRN)];
        ar = make_float4(gp.x / (float)WW, gp.y / (float)HH,
                         gp.z / (float)WW, gp.w / (float)HH);
    }

    // _xy2cxcy (reference halves wh too) then _encode then /std
    float acx = (ar.z + ar.x) / 2.0f, acy = (ar.w + ar.y) / 2.0f;
    float aw  = (ar.z - ar.x) / 2.0f, ah  = (ar.w - ar.y) / 2.0f;
    float gcx = (tb.z + tb.x) / 2.0f, gcy = (tb.w + tb.y) / 2.0f;
    float gw  = (tb.z - tb.x) / 2.0f, gh  = (tb.w - tb.y) / 2.0f;

    float e0 = ((gcx - acx) / aw) / 0.1f;
    float e1 = ((gcy - acy) / ah) / 0.1f;
    float e2 = logf(gw / aw) / 0.2f;
    float e3 = logf(gh / ah) / 0.2f;

    int gid = b * NUM_TOTAL + s;
    out[gid] = (float)label;
    float* eo = out + BB * NUM_TOTAL + gid * 4;
    eo[0] = e0; eo[1] = e1; eo[2] = e2; eo[3] = e3;
    float* ro = out + BB * NUM_TOTAL + BB * NUM_TOTAL * 4 + gid * 4;
    ro[0] = ar.x; ro[1] = ar.y; ro[2] = ar.z; ro[3] = ar.w;
}

// ---------------------------------------------------------------------------
// Kernel 2: exact stable top-k selection by random key + fused gather/encode.
// 16 blocks: (b, type). type 0 = positives (k = min(pc,32), slots [0,np)),
// type 1 = negatives (k = min(N-pc, 128-np), slots [np,np+k)) + tail (id=0).
// Histogram skips bins >= key 0.25 (can't contain k<=128 smallest of ~16.6k
// uniform keys); exact fallback rebuilds full histogram if low-bin total < k.
// ---------------------------------------------------------------------------
__global__ __launch_bounds__(SEL_T) void select_kernel(const uint32_t* __restrict__ codes,
                                                       const float* __restrict__ rp,
                                                       const float* __restrict__ rn,
                                                       const float* __restrict__ gt,
                                                       const int* __restrict__ gl,
                                                       const float* __restrict__ rois,
                                                       float* __restrict__ out) {
    __shared__ unsigned hist[1024];
    __shared__ uint32_t cbits[CAP];
    __shared__ int cidx[CAP];
    __shared__ int s_pc, s_cnt, s_k, s_np, s_p, s_total;

    int b = blockIdx.x >> 1;
    int t = blockIdx.x & 1;
    int tid = threadIdx.x;
    const float* rnd = (t == 0) ? rp : rn;
    const uint4* c4p = reinterpret_cast<const uint4*>(codes + b * NN);
    const float4* r4p = reinterpret_cast<const float4*>(rnd + b * NN);

    if (tid == 0) { s_pc = 0; s_cnt = 0; }
    __syncthreads();

    // --- pivot search (two attempts: cutoff'd histogram, then full if short) ---
    unsigned cutoff = 1000;  // bin 1000 <=> key 0.25 (float bits >> 20)
    for (int attempt = 0; attempt < 2; ++attempt) {
        hist[tid] = 0u;
        if (tid == 0) s_p = -1;
        __syncthreads();

        int myPos = 0;
        for (int v = tid; v < NV; v += SEL_T) {
            uint4 c4 = c4p[v];
            float4 r4 = r4p[v];
            uint32_t cc[4] = {c4.x, c4.y, c4.z, c4.w};
            float rr[4] = {r4.x, r4.y, r4.z, r4.w};
#pragma unroll
            for (int e = 0; e < 4; ++e) {
                bool isPos = (cc[e] & 0x10000u) != 0u;
                myPos += isPos ? 1 : 0;
                bool m = (t == 0) ? isPos : !isPos;
                if (m) {
                    unsigned bin = __float_as_uint(rr[e]) >> 20;
                    if (bin < cutoff) atomicAdd(&hist[bin], 1u);
                }
            }
        }
        if (attempt == 0) {  // count positives once (wave reduce + 16 atomics)
            for (int o = 32; o; o >>= 1) myPos += __shfl_down(myPos, o, 64);
            if ((tid & 63) == 0) atomicAdd(&s_pc, myPos);
        }
        __syncthreads();

        // parallel inclusive prefix scan over 1024 bins (Hillis-Steele)
        for (int off = 1; off < 1024; off <<= 1) {
            unsigned v = (tid >= off) ? hist[tid - off] : 0u;
            __syncthreads();
            hist[tid] += v;
            __syncthreads();
        }

        if (tid == 0) {
            int pc = s_pc;
            int np_ = min(pc, NUM_POS_MAX);
            int k = (t == 0) ? np_ : min(NN - pc, NUM_TOTAL - np_);
            s_np = np_;
            s_k = k;
            s_total = (int)hist[1023];
        }
        __syncthreads();

        int k = s_k;
        if (k > 0 && (int)hist[tid] >= k && (tid == 0 || (int)hist[tid - 1] < k))
            s_p = tid;  // unique writer: first bin with cum >= k
        __syncthreads();

        if (s_k == 0 || s_total >= s_k) break;
        cutoff = 1024;  // pathological: rebuild full histogram
    }

    int p = s_p;
    int k = s_k;
    int np_ = s_np;

    // --- collect candidates (bin <= pivot) ---
    if (p >= 0) {
        for (int v = tid; v < NV; v += SEL_T) {
            uint4 c4 = c4p[v];
            float4 r4 = r4p[v];
            uint32_t cc[4] = {c4.x, c4.y, c4.z, c4.w};
            float rr[4] = {r4.x, r4.y, r4.z, r4.w};
#pragma unroll
            for (int e = 0; e < 4; ++e) {
                bool isPos = (cc[e] & 0x10000u) != 0u;
                bool m = (t == 0) ? isPos : !isPos;
                if (m) {
                    uint32_t bits = __float_as_uint(rr[e]);
                    if ((int)(bits >> 20) <= p) {
                        int ix = atomicAdd(&s_cnt, 1);
                        if (ix < CAP) { cbits[ix] = bits; cidx[ix] = v * 4 + e; }
                    }
                }
            }
        }
    }
    __syncthreads();

    // --- exact stable ranking + fused gather/encode ---
    int c = min(s_cnt, CAP);
    for (int ci = tid; ci < c; ci += SEL_T) {
        uint32_t mb = cbits[ci];
        int mi = cidx[ci];
        int r = 0;
        for (int j = 0; j < c; ++j) {
            uint32_t ob = cbits[j];
            r += ((ob < mb) || (ob == mb && cidx[j] < mi)) ? 1 : 0;  // stable
        }
        if (r < k) {
            int s = (t == 0) ? r : (np_ + r);
            write_sample(b, s, mi, np_, gt, gl, rois, codes, out);
        }
    }

    // --- neg block fills tail slots [np+k, 128) with id 0 (reference: slot
    //     stays 0 -> sampled_ids 0 -> element 0 gathered, label 0) ---
    if (t == 1) {
        for (int s = np_ + k + tid; s < NUM_TOTAL; s += SEL_T)
            write_sample(b, s, 0, np_, gt, gl, rois, codes, out);
    }
}

// ---------------------------------------------------------------------------
extern "C" void kernel_launch(void* const* d_in, const int* in_sizes, int n_in,
                              void* d_out, int out_size, void* d_ws, size_t ws_size,
                              hipStream_t stream) {
    const float* gt   = (const float*)d_in[0];   // (B,G,4) f32
    const int*   gl   = (const int*)d_in[1];     // (B,G)   i32
    const float* rois = (const float*)d_in[2];   // (B,R,4) f32
    const float* rp   = (const float*)d_in[3];   // (B,N)   f32
    const float* rn   = (const float*)d_in[4];   // (B,N)   f32
    float* out = (float*)d_out;

    uint32_t* codes = (uint32_t*)d_ws;  // B*N u32 (fully rewritten every call)

    hipLaunchKernelGGL(iou_kernel, dim3(BB * 65), dim3(256), 0, stream,
                       gt, rois, codes);
    hipLaunchKernelGGL(select_kernel, dim3(BB * 2), dim3(SEL_T), 0, stream,
                       codes, rp, rn, gt, gl, rois, out);
}

// Round 7
// 103.549 us; speedup vs baseline: 2.0347x; 1.1030x over previous
//
#include <hip/hip_runtime.h>
#include <stdint.h>

// Problem constants (match reference)
#define HH 1024
#define WW 2048
#define GG 256          // gt boxes per image
#define RRN 16384       // rois per image
#define NN 16640        // R + G, = 65*256 exactly
#define NV (NN / 4)     // 4160 uint4/float4 vectors per image
#define BB 8
#define NUM_POS_MAX 32
#define NUM_TOTAL 128
#define CAP 1024        // candidate capacity in select kernel
#define SEL_T 1024      // select block size
#define CUT_BITS 0x3C800000u  // float bits of 1/64: speculative key cutoff

// ---------------------------------------------------------------------------
// Kernel 1: per-roi IoU max/argmax vs 256 gt boxes
// codes[b*N+i] = argmax | (pos ? 0x10000 : 0)
// Early-out: inter==0 -> iou == +0 exactly (denom >= gt area >= 4 > 0), and a
// zero iou can only set best at j==0 (best starts -1). So j=0 is peeled and
// the j>=1 body only enters the div path when inter > 0 -- a wave-uniformly
// false branch on this data (pixel gt vs normalized rois), skipped by execz.
// Bit-identical to the dense reference loop.
// ---------------------------------------------------------------------------
__global__ __launch_bounds__(256) void iou_kernel(const float* __restrict__ gt,
                                                  const float* __restrict__ rois,
                                                  uint32_t* __restrict__ codes) {
#pragma clang fp contract(off)
    __shared__ float4 sg[GG];
    int b = blockIdx.x / 65;
    int chunk = blockIdx.x % 65;
    int tid = threadIdx.x;

    sg[tid] = reinterpret_cast<const float4*>(gt)[b * GG + tid];
    __syncthreads();

    int i = chunk * 256 + tid;  // 0..N-1, exact (N = 65*256)
    float4 rb;
    if (i < RRN) {
        rb = reinterpret_cast<const float4*>(rois)[b * RRN + i];
    } else {
        float4 gp = sg[i - RRN];
        rb = make_float4(gp.x / (float)WW, gp.y / (float)HH,
                         gp.z / (float)WW, gp.w / (float)HH);
    }
    float a1 = fmaxf((rb.z - rb.x) * (rb.w - rb.y), 0.0f);

    float best;
    int bestj = 0;
    {   // j = 0 peeled: handles the best=-1 -> 0 transition exactly
        float4 gj = sg[0];
        float lx = fmaxf(rb.x, gj.x), ly = fmaxf(rb.y, gj.y);
        float ux = fminf(rb.z, gj.z), uy = fminf(rb.w, gj.w);
        float iw = fmaxf(ux - lx, 0.0f), ih = fmaxf(uy - ly, 0.0f);
        float inter = iw * ih;
        if (inter > 0.0f) {
            float a2 = fmaxf((gj.z - gj.x) * (gj.w - gj.y), 0.0f);
            float denom = (a1 + a2) - inter;
            best = inter / denom;   // > 0 > -1: always the j=0 update
        } else {
            best = 0.0f;            // iou == +0 exactly; bestj stays 0
        }
    }
#pragma unroll 4
    for (int j = 1; j < GG; ++j) {
        float4 gj = sg[j];
        float lx = fmaxf(rb.x, gj.x), ly = fmaxf(rb.y, gj.y);
        float ux = fminf(rb.z, gj.z), uy = fminf(rb.w, gj.w);
        float iw = fmaxf(ux - lx, 0.0f), ih = fmaxf(uy - ly, 0.0f);
        float inter = iw * ih;
        if (inter > 0.0f) {         // zero-iou can never beat best >= 0
            float a2 = fmaxf((gj.z - gj.x) * (gj.w - gj.y), 0.0f);
            float denom = (a1 + a2) - inter;
            float iou = inter / denom;
            if (iou > best) { best = iou; bestj = j; }  // strict >: first max
        }
    }

    bool pos = (best >= 0.5f);  // POS_THR; neg == !pos since iou_max >= 0
    codes[b * NN + i] = (uint32_t)bestj | (pos ? 0x10000u : 0u);
}

// ---------------------------------------------------------------------------
// Epilogue: write one sampled slot (label + encoded bbox + sampled roi)
// Output layout (all f32, concatenated): [0,1024) labels, [1024,5120) encoded,
// [5120,9216) sampled rois.
// ---------------------------------------------------------------------------
__device__ __forceinline__ void write_sample(int b, int s, int mi, int np,
                                             const float* __restrict__ gt,
                                             const int* __restrict__ gl,
                                             const float* __restrict__ rois,
                                             const uint32_t* __restrict__ codes,
                                             float* __restrict__ out) {
#pragma clang fp contract(off)
    uint32_t code = codes[b * NN + mi];
    int amax = (int)(code & 0xFFFFu);
    int label = (s < np) ? (gl[b * GG + amax] + 1) : 0;

    float4 tb = reinterpret_cast<const float4*>(gt)[b * GG + amax];  // pixel gt
    float4 ar;
    if (mi < RRN) {
        ar = reinterpret_cast<const float4*>(rois)[b * RRN + mi];
    } else {
        float4 gp = reinterpret_cast<const float4*>(gt)[b * GG + (mi - RRN)];
        ar = make_float4(gp.x / (float)WW, gp.y / (float)HH,
                         gp.z / (float)WW, gp.w / (float)HH);
    }

    // _xy2cxcy (reference halves wh too) then _encode then /std
    float acx = (ar.z + ar.x) / 2.0f, acy = (ar.w + ar.y) / 2.0f;
    float aw  = (ar.z - ar.x) / 2.0f, ah  = (ar.w - ar.y) / 2.0f;
    float gcx = (tb.z + tb.x) / 2.0f, gcy = (tb.w + tb.y) / 2.0f;
    float gw  = (tb.z - tb.x) / 2.0f, gh  = (tb.w - tb.y) / 2.0f;

    float e0 = ((gcx - acx) / aw) / 0.1f;
    float e1 = ((gcy - acy) / ah) / 0.1f;
    float e2 = logf(gw / aw) / 0.2f;
    float e3 = logf(gh / ah) / 0.2f;

    int gid = b * NUM_TOTAL + s;
    out[gid] = (float)label;
    float* eo = out + BB * NUM_TOTAL + gid * 4;
    eo[0] = e0; eo[1] = e1; eo[2] = e2; eo[3] = e3;
    float* ro = out + BB * NUM_TOTAL + BB * NUM_TOTAL * 4 + gid * 4;
    ro[0] = ar.x; ro[1] = ar.y; ro[2] = ar.z; ro[3] = ar.w;
}

// ---------------------------------------------------------------------------
// Kernel 2: exact stable top-k by random key + fused gather/encode.
// 16 blocks: (b, type). Fast path: single pass collecting all mask elements
// with key < 1/64 (expected ~258 of ~16.5k uniforms; k <= 128), plus pos
// count. If count >= k (k-th smallest is < 1/64 -> all top-k collected) and
// count <= CAP, rank candidates exactly by (bits, idx) -- no histogram, no
// prefix scan, no second pass. Exact histogram fallback otherwise.
// ---------------------------------------------------------------------------
__global__ __launch_bounds__(SEL_T) void select_kernel(const uint32_t* __restrict__ codes,
                                                       const float* __restrict__ rp,
                                                       const float* __restrict__ rn,
                                                       const float* __restrict__ gt,
                                                       const int* __restrict__ gl,
                                                       const float* __restrict__ rois,
                                                       float* __restrict__ out) {
    __shared__ unsigned hist[1024];
    __shared__ uint32_t cbits[CAP];
    __shared__ int cidx[CAP];
    __shared__ int s_pc, s_cnt, s_p;

    int b = blockIdx.x >> 1;
    int t = blockIdx.x & 1;
    int tid = threadIdx.x;
    const float* rnd = (t == 0) ? rp : rn;
    const uint4* c4p = reinterpret_cast<const uint4*>(codes + b * NN);
    const float4* r4p = reinterpret_cast<const float4*>(rnd + b * NN);

    if (tid == 0) { s_pc = 0; s_cnt = 0; }
    __syncthreads();

    // --- pass 1: pos count + speculative candidate collection (key < 1/64) ---
    int myPos = 0;
    for (int v = tid; v < NV; v += SEL_T) {
        uint4 c4 = c4p[v];
        float4 r4 = r4p[v];
        uint32_t cc[4] = {c4.x, c4.y, c4.z, c4.w};
        float rr[4] = {r4.x, r4.y, r4.z, r4.w};
#pragma unroll
        for (int e = 0; e < 4; ++e) {
            bool isPos = (cc[e] & 0x10000u) != 0u;
            myPos += isPos ? 1 : 0;
            bool m = (t == 0) ? isPos : !isPos;
            if (m) {
                uint32_t bits = __float_as_uint(rr[e]);  // keys in [0,1): bit order == float order
                if (bits < CUT_BITS) {
                    int ix = atomicAdd(&s_cnt, 1);       // s_cnt = TRUE count (even past CAP)
                    if (ix < CAP) { cbits[ix] = bits; cidx[ix] = v * 4 + e; }
                }
            }
        }
    }
    for (int o = 32; o; o >>= 1) myPos += __shfl_down(myPos, o, 64);
    if ((tid & 63) == 0) atomicAdd(&s_pc, myPos);
    __syncthreads();

    int pc = s_pc;
    int np_ = min(pc, NUM_POS_MAX);
    int k = (t == 0) ? np_ : min(NN - pc, NUM_TOTAL - np_);
    int total = s_cnt;
    bool fast = (total >= k) && (total <= CAP);

    if (!fast) {
        // --- exact fallback: full histogram + prefix scan + pivot + recollect ---
        hist[tid] = 0u;
        if (tid == 0) { s_cnt = 0; s_p = -1; }
        __syncthreads();
        for (int v = tid; v < NV; v += SEL_T) {
            uint4 c4 = c4p[v];
            float4 r4 = r4p[v];
            uint32_t cc[4] = {c4.x, c4.y, c4.z, c4.w};
            float rr[4] = {r4.x, r4.y, r4.z, r4.w};
#pragma unroll
            for (int e = 0; e < 4; ++e) {
                bool isPos = (cc[e] & 0x10000u) != 0u;
                bool m = (t == 0) ? isPos : !isPos;
                if (m) atomicAdd(&hist[__float_as_uint(rr[e]) >> 20], 1u);
            }
        }
        __syncthreads();
        for (int off = 1; off < 1024; off <<= 1) {  // Hillis-Steele inclusive scan
            unsigned v = (tid >= off) ? hist[tid - off] : 0u;
            __syncthreads();
            hist[tid] += v;
            __syncthreads();
        }
        if (k > 0 && (int)hist[tid] >= k && (tid == 0 || (int)hist[tid - 1] < k))
            s_p = tid;  // unique writer: first bin with cum >= k
        __syncthreads();
        int p = s_p;
        if (p >= 0) {
            for (int v = tid; v < NV; v += SEL_T) {
                uint4 c4 = c4p[v];
                float4 r4 = r4p[v];
                uint32_t cc[4] = {c4.x, c4.y, c4.z, c4.w};
                float rr[4] = {r4.x, r4.y, r4.z, r4.w};
#pragma unroll
                for (int e = 0; e < 4; ++e) {
                    bool isPos = (cc[e] & 0x10000u) != 0u;
                    bool m = (t == 0) ? isPos : !isPos;
                    if (m) {
                        uint32_t bits = __float_as_uint(rr[e]);
                        if ((int)(bits >> 20) <= p) {
                            int ix = atomicAdd(&s_cnt, 1);
                            if (ix < CAP) { cbits[ix] = bits; cidx[ix] = v * 4 + e; }
                        }
                    }
                }
            }
        }
        __syncthreads();
    }

    // --- exact stable ranking among candidates + fused gather/encode ---
    int c = min(s_cnt, CAP);
    for (int ci = tid; ci < c; ci += SEL_T) {
        uint32_t mb = cbits[ci];
        int mi = cidx[ci];
        int r = 0;
        for (int j = 0; j < c; ++j) {
            uint32_t ob = cbits[j];
            r += ((ob < mb) || (ob == mb && cidx[j] < mi)) ? 1 : 0;  // stable
        }
        if (r < k) {
            int s = (t == 0) ? r : (np_ + r);
            write_sample(b, s, mi, np_, gt, gl, rois, codes, out);
        }
    }

    // --- neg block fills tail slots [np+k, 128) with id 0 (reference: slot
    //     stays 0 -> sampled_ids 0 -> element 0 gathered, label 0) ---
    if (t == 1) {
        for (int s = np_ + k + tid; s < NUM_TOTAL; s += SEL_T)
            write_sample(b, s, 0, np_, gt, gl, rois, codes, out);
    }
}

// ---------------------------------------------------------------------------
extern "C" void kernel_launch(void* const* d_in, const int* in_sizes, int n_in,
                              void* d_out, int out_size, void* d_ws, size_t ws_size,
                              hipStream_t stream) {
    const float* gt   = (const float*)d_in[0];   // (B,G,4) f32
    const int*   gl   = (const int*)d_in[1];     // (B,G)   i32
    const float* rois = (const float*)d_in[2];   // (B,R,4) f32
    const float* rp   = (const float*)d_in[3];   // (B,N)   f32
    const float* rn   = (const float*)d_in[4];   // (B,N)   f32
    float* out = (float*)d_out;

    uint32_t* codes = (uint32_t*)d_ws;  // B*N u32 (fully rewritten every call)

    hipLaunchKernelGGL(iou_kernel, dim3(BB * 65), dim3(256), 0, stream,
                       gt, rois, codes);
    hipLaunchKernelGGL(select_kernel, dim3(BB * 2), dim3(SEL_T), 0, stream,
                       codes, rp, rn, gt, gl, rois, out);
}